// Round 1
// baseline (281.584 us; speedup 1.0000x reference)
//
#include <hip/hip_runtime.h>
#include <hip/hip_bf16.h>

typedef unsigned short u16;
typedef __attribute__((ext_vector_type(4))) float f32x4;
typedef __attribute__((ext_vector_type(8))) short short8;

#define BN_EPS 1e-5f

__device__ __forceinline__ u16 f2b(float x) {
  union { float f; unsigned int u; } v; v.f = x;
  unsigned int r = (v.u + 0x7FFFu + ((v.u >> 16) & 1u)) >> 16;
  return (u16)r;
}
__device__ __forceinline__ float b2f(u16 u) {
  union { unsigned int u; float f; } v; v.u = ((unsigned int)u) << 16;
  return v.f;
}

// ---------------------------------------------------------------------------
// prep: fold BN into alpha/beta; convert W1/W2 to bf16 in blocked [kt][o][32k]
// ---------------------------------------------------------------------------
__global__ void prep_kernel(const float* __restrict__ w1, const float* __restrict__ b1,
                            const float* __restrict__ g1, const float* __restrict__ be1,
                            const float* __restrict__ m1, const float* __restrict__ v1,
                            const float* __restrict__ w2, const float* __restrict__ b2,
                            const float* __restrict__ g2, const float* __restrict__ be2,
                            const float* __restrict__ m2, const float* __restrict__ v2,
                            u16* __restrict__ w1b, u16* __restrict__ w2b,
                            float* __restrict__ al1, float* __restrict__ bt1,
                            float* __restrict__ al2, float* __restrict__ bt2) {
  int t = threadIdx.x;
  int blk = blockIdx.x;
  if (blk < 384) {                       // w1: 256x384
    int id = blk * 256 + t;
    unsigned o = (unsigned)id / 384u;
    unsigned c = (unsigned)id % 384u;
    w1b[(c >> 5) * 8192 + o * 32 + (c & 31)] = f2b(w1[id]);
  } else if (blk < 640) {                // w2: 256x256
    int j = (blk - 384) * 256 + t;
    unsigned o = (unsigned)j >> 8;
    unsigned c = (unsigned)j & 255u;
    w2b[(c >> 5) * 8192 + o * 32 + (c & 31)] = f2b(w2[j]);
  } else if (blk == 640) {
    float a = g1[t] / sqrtf(v1[t] + BN_EPS);
    al1[t] = a;
    bt1[t] = (b1[t] - m1[t]) * a + be1[t];
  } else {
    float a = g2[t] / sqrtf(v2[t] + BN_EPS);
    al2[t] = a;
    bt2[t] = (b2[t] - m2[t]) * a + be2[t];
  }
}

// ---------------------------------------------------------------------------
// transpose features2 [B][256][2048] f32 -> f2t [B][2048][256] bf16
// ---------------------------------------------------------------------------
__global__ void transpose_f2_kernel(const float* __restrict__ f2, u16* __restrict__ f2t) {
  __shared__ float tile[32][33];
  int t = threadIdx.x;
  int tx = t & 31, ty = t >> 5;          // ty in [0,8)
  int b = blockIdx.z;
  int n2t = blockIdx.x * 32, ct = blockIdx.y * 32;
#pragma unroll
  for (int i = 0; i < 4; ++i) {
    int c = ct + ty + i * 8;
    tile[ty + i * 8][tx] = f2[((size_t)b * 256 + c) * 2048 + n2t + tx];
  }
  __syncthreads();
#pragma unroll
  for (int i = 0; i < 4; ++i) {
    int n2 = n2t + ty + i * 8;
    f2t[((size_t)b * 2048 + n2) * 256 + ct + tx] = f2b(tile[tx][ty + i * 8]);
  }
}

// ---------------------------------------------------------------------------
// knn + interp + skip-copy. One block = one batch x 64 query points.
// xb blocked layout: [panel][kt(12)][n(64)][kc(32)] bf16, panel = bn/64.
// ---------------------------------------------------------------------------
__global__ __launch_bounds__(256) void knn_interp_kernel(
    const float* __restrict__ xyz1, const float* __restrict__ xyz2,
    const float* __restrict__ f1, const u16* __restrict__ f2t,
    u16* __restrict__ xb) {
#pragma clang fp contract(off)
  union Lds {
    struct { float4 pts[2048]; float md[256 * 3]; int mi[256 * 3]; } a;
    float f1t[128 * 65];
  };
  __shared__ Lds lds;
  __shared__ float wts[64 * 3];
  __shared__ int idxs[64 * 3];

  int t = threadIdx.x;
  int b = blockIdx.x >> 7;
  int n1_0 = (blockIdx.x & 127) * 64;
  int panel = blockIdx.x;                // = b*128 + tile

  // phase 0: stage candidates (x,y,z,|x|^2)
  const float* x2 = xyz2 + b * 3 * 2048;
  for (int j = t; j < 2048; j += 256) {
    float cx = x2[j], cy = x2[2048 + j], cz = x2[4096 + j];
    float nsq = (cx * cx + cy * cy) + cz * cz;
    lds.a.pts[j] = make_float4(cx, cy, cz, nsq);
  }
  __syncthreads();

  // phase 1: 4-way sliced top-3 per query (contiguous slices keep tie order)
  {
    int p = t >> 2, s = t & 3;
    int n1 = n1_0 + p;
    const float* x1 = xyz1 + b * 3 * 8192;
    float bx = x1[n1], by = x1[8192 + n1], bz = x1[16384 + n1];
    float n1sq = (bx * bx + by * by) + bz * bz;
    float d0 = 3.4e38f, d1 = 3.4e38f, d2 = 3.4e38f;
    int i0 = 0, i1 = 0, i2 = 0;
    for (int j = s * 512; j < s * 512 + 512; ++j) {
      float4 c = lds.a.pts[j];
      float dot = (bx * c.x + by * c.y) + bz * c.z;
      float sq = (n1sq + c.w) - 2.0f * dot;
      bool c0 = sq < d0, c1 = sq < d1, c2 = sq < d2;
      d2 = c1 ? d1 : (c2 ? sq : d2);  i2 = c1 ? i1 : (c2 ? j : i2);
      d1 = c0 ? d0 : (c1 ? sq : d1); i1 = c0 ? i0 : (c1 ? j : i1);
      d0 = c0 ? sq : d0;             i0 = c0 ? j : i0;
    }
    lds.a.md[t * 3 + 0] = d0; lds.a.md[t * 3 + 1] = d1; lds.a.md[t * 3 + 2] = d2;
    lds.a.mi[t * 3 + 0] = i0; lds.a.mi[t * 3 + 1] = i1; lds.a.mi[t * 3 + 2] = i2;
  }
  __syncthreads();
  if (t < 64) {
    float d0 = 3.4e38f, d1 = 3.4e38f, d2 = 3.4e38f;
    int i0 = 0, i1 = 0, i2 = 0;
#pragma unroll
    for (int s = 0; s < 4; ++s) {
#pragma unroll
      for (int k = 0; k < 3; ++k) {
        float d = lds.a.md[(t * 4 + s) * 3 + k];
        int i = lds.a.mi[(t * 4 + s) * 3 + k];
        bool c0 = d < d0, c1 = d < d1, c2 = d < d2;
        d2 = c1 ? d1 : (c2 ? d : d2);  i2 = c1 ? i1 : (c2 ? i : i2);
        d1 = c0 ? d0 : (c1 ? d : d1); i1 = c0 ? i0 : (c1 ? i : i1);
        d0 = c0 ? d : d0;             i0 = c0 ? i : i0;
      }
    }
    float e0 = fmaxf(d0, 1e-10f), e1 = fmaxf(d1, 1e-10f), e2 = fmaxf(d2, 1e-10f);
    float w0 = 1.0f / e0, w1 = 1.0f / e1, w2 = 1.0f / e2;
    float sm = (w0 + w1) + w2;
    wts[t * 3 + 0] = w0 / sm; wts[t * 3 + 1] = w1 / sm; wts[t * 3 + 2] = w2 / sm;
    idxs[t * 3 + 0] = i0; idxs[t * 3 + 1] = i1; idxs[t * 3 + 2] = i2;
  }
  __syncthreads();

  // phase 2: interp 256 channels (thread = channel), write xb blocked
  {
    const u16* f2tb = f2t + (size_t)b * 2048 * 256;
    size_t xbase = (size_t)panel * 24576 + (size_t)((t >> 5) * 2048) + (t & 31);
    for (int p = 0; p < 64; ++p) {
      int j0 = idxs[p * 3 + 0], j1 = idxs[p * 3 + 1], j2 = idxs[p * 3 + 2];
      float w0 = wts[p * 3 + 0], w1 = wts[p * 3 + 1], w2 = wts[p * 3 + 2];
      float v = (w0 * b2f(f2tb[j0 * 256 + t]) + w1 * b2f(f2tb[j1 * 256 + t]))
                + w2 * b2f(f2tb[j2 * 256 + t]);
      xb[xbase + p * 32] = f2b(v);
    }
  }
  __syncthreads();   // before aliasing lds.a with lds.f1t

  // phase 3: skip features (channels 256..383) via LDS transpose
  {
    const float* f1b = f1 + (size_t)b * 128 * 8192 + n1_0;
    for (int it = 0; it < 32; ++it) {
      int c = it * 4 + (t >> 6);
      int n = t & 63;
      lds.f1t[c * 65 + n] = f1b[(size_t)c * 8192 + n];
    }
    __syncthreads();
    for (int it = 0; it < 32; ++it) {
      int v = it * 256 + t;
      int c = v & 127, p = v >> 7;
      float val = lds.f1t[c * 65 + p];
      xb[(size_t)panel * 24576 + (size_t)(8 + (c >> 5)) * 2048 + p * 32 + (c & 31)] = f2b(val);
    }
  }
}

// ---------------------------------------------------------------------------
// GEMM: out[o][bn] = act(alpha[o]*sum_k W[o][k]*x[k][bn] + beta[o])
// block: 256 threads (4 waves), tile 256(o) x 64(n), BK=32, mfma 16x16x32 bf16
// wb blocked [kt][256][32]; x blocked [panel][kt][64][32].
// FINAL=false -> write bf16 y blocked [panel][kt=o/32][64][32]
// FINAL=true  -> write f32 out [b][256][8192]
// ---------------------------------------------------------------------------
template <int KT, bool FINAL>
__global__ __launch_bounds__(256) void gemm_kernel(
    const u16* __restrict__ xin, const u16* __restrict__ wb,
    const float* __restrict__ alpha, const float* __restrict__ beta,
    u16* __restrict__ yout, float* __restrict__ fout) {
  union Lds {
    struct { u16 A[256 * 40]; u16 B[64 * 40]; } s;
    u16 Y[256 * 64];
  };
  __shared__ Lds lds;
  int t = threadIdx.x;
  int panel = blockIdx.x;
  int w = t >> 6, lane = t & 63, l15 = lane & 15, quad = lane >> 4;

  f32x4 acc[4][4];
#pragma unroll
  for (int m = 0; m < 4; ++m)
#pragma unroll
    for (int n = 0; n < 4; ++n)
      acc[m][n] = (f32x4){0.f, 0.f, 0.f, 0.f};

  for (int kt = 0; kt < KT; ++kt) {
    // stage A: 16 KB, fully linear
    const uint4* ga = (const uint4*)(wb + (size_t)kt * 8192);
#pragma unroll
    for (int p2 = 0; p2 < 4; ++p2) {
      int s2 = p2 * 256 + t;             // slot: o = s2>>2, kh = s2&3
      uint4 v = ga[s2];
      *(uint4*)&lds.s.A[(s2 >> 2) * 40 + (s2 & 3) * 8] = v;
    }
    // stage B: 4 KB, fully linear
    {
      const uint4* gb = (const uint4*)(xin + (size_t)(panel * KT + kt) * 2048);
      uint4 v = gb[t];                   // n = t>>2, kq = t&3
      *(uint4*)&lds.s.B[(t >> 2) * 40 + (t & 3) * 8] = v;
    }
    __syncthreads();
    short8 af[4], bfr[4];
#pragma unroll
    for (int m = 0; m < 4; ++m)
      af[m] = *(const short8*)&lds.s.A[(w * 64 + m * 16 + l15) * 40 + quad * 8];
#pragma unroll
    for (int n = 0; n < 4; ++n)
      bfr[n] = *(const short8*)&lds.s.B[(n * 16 + l15) * 40 + quad * 8];
    __syncthreads();
#pragma unroll
    for (int m = 0; m < 4; ++m)
#pragma unroll
      for (int n = 0; n < 4; ++n)
        acc[m][n] = __builtin_amdgcn_mfma_f32_16x16x32_bf16(af[m], bfr[n], acc[m][n], 0, 0, 0);
  }

  float al[4][4], bt[4][4];
#pragma unroll
  for (int m = 0; m < 4; ++m)
#pragma unroll
    for (int r = 0; r < 4; ++r) {
      int o = w * 64 + m * 16 + quad * 4 + r;
      al[m][r] = alpha[o];
      bt[m][r] = beta[o];
    }

  if (FINAL) {
#pragma unroll
    for (int m = 0; m < 4; ++m)
#pragma unroll
      for (int n = 0; n < 4; ++n)
#pragma unroll
        for (int r = 0; r < 4; ++r) {
          int o = w * 64 + m * 16 + quad * 4 + r;
          int col = n * 16 + l15;
          int bn = panel * 64 + col;
          int bb = bn >> 13, n1 = bn & 8191;
          float vv = fmaxf(al[m][r] * acc[m][n][r] + bt[m][r], 0.f);
          fout[(size_t)(bb * 256 + o) * 8192 + n1] = vv;
        }
  } else {
    // emit bf16 into LDS in the blocked layout, then linear 16B copies out
#pragma unroll
    for (int m = 0; m < 4; ++m)
#pragma unroll
      for (int n = 0; n < 4; ++n)
#pragma unroll
        for (int r = 0; r < 4; ++r) {
          int o = w * 64 + m * 16 + quad * 4 + r;
          int col = n * 16 + l15;
          float vv = fmaxf(al[m][r] * acc[m][n][r] + bt[m][r], 0.f);
          lds.Y[((o >> 5) * 64 + col) * 32 + (o & 31)] = f2b(vv);
        }
    __syncthreads();
    uint4* gy = (uint4*)(yout + (size_t)panel * 16384);
    const uint4* ly = (const uint4*)lds.Y;
#pragma unroll
    for (int i = 0; i < 8; ++i)
      gy[i * 256 + t] = ly[i * 256 + t];
  }
}

// ---------------------------------------------------------------------------
// ws layout (bytes):
//   [0,          50331648)  xb   bf16 [1024 panels][12][64][32]   48 MB
//   [50331648,   83886080)  y1   bf16 [1024][8][64][32]           32 MB
//      (f2t bf16 8 MB aliases the start of y1 — dead before y1 is written)
//   [83886080,   84082688)  w1b  bf16 blocked
//   [84082688,   84213760)  w2b  bf16 blocked
//   [84213760,   84217856)  al1/bt1/al2/bt2 f32
// total ~80.3 MB
// ---------------------------------------------------------------------------
extern "C" void kernel_launch(void* const* d_in, const int* in_sizes, int n_in,
                              void* d_out, int out_size, void* d_ws, size_t ws_size,
                              hipStream_t stream) {
  const float* xyz1 = (const float*)d_in[0];
  const float* xyz2 = (const float*)d_in[1];
  const float* f1   = (const float*)d_in[2];
  const float* f2   = (const float*)d_in[3];
  const float* w1   = (const float*)d_in[4];
  const float* b1   = (const float*)d_in[5];
  const float* g1   = (const float*)d_in[6];
  const float* be1  = (const float*)d_in[7];
  const float* m1   = (const float*)d_in[8];
  const float* v1   = (const float*)d_in[9];
  const float* w2   = (const float*)d_in[10];
  const float* b2   = (const float*)d_in[11];
  const float* g2   = (const float*)d_in[12];
  const float* be2  = (const float*)d_in[13];
  const float* m2   = (const float*)d_in[14];
  const float* v2   = (const float*)d_in[15];

  char* ws = (char*)d_ws;
  u16* xb   = (u16*)(ws);
  u16* y1   = (u16*)(ws + 50331648);
  u16* f2t  = (u16*)(ws + 50331648);   // aliases y1 region; dead before y1 write
  u16* w1b  = (u16*)(ws + 83886080);
  u16* w2b  = (u16*)(ws + 84082688);
  float* al1 = (float*)(ws + 84213760);
  float* bt1 = (float*)(ws + 84214784);
  float* al2 = (float*)(ws + 84215808);
  float* bt2 = (float*)(ws + 84216832);
  float* out = (float*)d_out;

  prep_kernel<<<642, 256, 0, stream>>>(w1, b1, g1, be1, m1, v1,
                                       w2, b2, g2, be2, m2, v2,
                                       w1b, w2b, al1, bt1, al2, bt2);
  transpose_f2_kernel<<<dim3(64, 8, 8), 256, 0, stream>>>(f2, f2t);
  knn_interp_kernel<<<1024, 256, 0, stream>>>(xyz1, xyz2, f1, f2t, xb);
  gemm_kernel<12, false><<<1024, 256, 0, stream>>>(xb, w1b, al1, bt1, y1, nullptr);
  gemm_kernel<8, true><<<1024, 256, 0, stream>>>(y1, w2b, al2, bt2, nullptr, out);
}

// Round 2
// 248.751 us; speedup vs baseline: 1.1320x; 1.1320x over previous
//
#include <hip/hip_runtime.h>
#include <hip/hip_bf16.h>

typedef unsigned short u16;
typedef __attribute__((ext_vector_type(4))) float f32x4;
typedef __attribute__((ext_vector_type(8))) short short8;

#define BN_EPS 1e-5f

__device__ __forceinline__ u16 f2b(float x) {
  union { float f; unsigned int u; } v; v.f = x;
  unsigned int r = (v.u + 0x7FFFu + ((v.u >> 16) & 1u)) >> 16;
  return (u16)r;
}
__device__ __forceinline__ float b2f(u16 u) {
  union { unsigned int u; float f; } v; v.u = ((unsigned int)u) << 16;
  return v.f;
}

// ---------------------------------------------------------------------------
// prep: fold BN into alpha/beta; convert W1/W2 to bf16 in blocked [kt][o][32k]
// ---------------------------------------------------------------------------
__global__ void prep_kernel(const float* __restrict__ w1, const float* __restrict__ b1,
                            const float* __restrict__ g1, const float* __restrict__ be1,
                            const float* __restrict__ m1, const float* __restrict__ v1,
                            const float* __restrict__ w2, const float* __restrict__ b2,
                            const float* __restrict__ g2, const float* __restrict__ be2,
                            const float* __restrict__ m2, const float* __restrict__ v2,
                            u16* __restrict__ w1b, u16* __restrict__ w2b,
                            float* __restrict__ al1, float* __restrict__ bt1,
                            float* __restrict__ al2, float* __restrict__ bt2) {
  int t = threadIdx.x;
  int blk = blockIdx.x;
  if (blk < 384) {                       // w1: 256x384
    int id = blk * 256 + t;
    unsigned o = (unsigned)id / 384u;
    unsigned c = (unsigned)id % 384u;
    w1b[(c >> 5) * 8192 + o * 32 + (c & 31)] = f2b(w1[id]);
  } else if (blk < 640) {                // w2: 256x256
    int j = (blk - 384) * 256 + t;
    unsigned o = (unsigned)j >> 8;
    unsigned c = (unsigned)j & 255u;
    w2b[(c >> 5) * 8192 + o * 32 + (c & 31)] = f2b(w2[j]);
  } else if (blk == 640) {
    float a = g1[t] / sqrtf(v1[t] + BN_EPS);
    al1[t] = a;
    bt1[t] = (b1[t] - m1[t]) * a + be1[t];
  } else {
    float a = g2[t] / sqrtf(v2[t] + BN_EPS);
    al2[t] = a;
    bt2[t] = (b2[t] - m2[t]) * a + be2[t];
  }
}

// ---------------------------------------------------------------------------
// transpose features2 [B][256][2048] f32 -> f2t [B][2048][256] bf16
// ---------------------------------------------------------------------------
__global__ void transpose_f2_kernel(const float* __restrict__ f2, u16* __restrict__ f2t) {
  __shared__ float tile[32][33];
  int t = threadIdx.x;
  int tx = t & 31, ty = t >> 5;          // ty in [0,8)
  int b = blockIdx.z;
  int n2t = blockIdx.x * 32, ct = blockIdx.y * 32;
#pragma unroll
  for (int i = 0; i < 4; ++i) {
    int c = ct + ty + i * 8;
    tile[ty + i * 8][tx] = f2[((size_t)b * 256 + c) * 2048 + n2t + tx];
  }
  __syncthreads();
#pragma unroll
  for (int i = 0; i < 4; ++i) {
    int n2 = n2t + ty + i * 8;
    f2t[((size_t)b * 2048 + n2) * 256 + ct + tx] = f2b(tile[tx][ty + i * 8]);
  }
}

// ---------------------------------------------------------------------------
// knn + interp + skip-copy. One block = one batch x 64 query points.
// Phase 1: lane = query (p = t&63), wave = slice (s = t>>6) -> every lane of a
// wave reads the SAME pts[j] (LDS broadcast, conflict-free; was 4-way before).
// xb blocked layout: [panel][kt(12)][n(64)][kc(32)] bf16, panel = bn/64.
// ---------------------------------------------------------------------------
__global__ __launch_bounds__(256) void knn_interp_kernel(
    const float* __restrict__ xyz1, const float* __restrict__ xyz2,
    const float* __restrict__ f1, const u16* __restrict__ f2t,
    u16* __restrict__ xb) {
  union Lds {
    struct { float4 pts[2048]; float md[256 * 3]; int mi[256 * 3]; } a;
    float f1t[128 * 65];
  };
  __shared__ Lds lds;
  __shared__ float wts[64 * 3];
  __shared__ int idxs[64 * 3];           // premultiplied by 256

  int t = threadIdx.x;
  int b = blockIdx.x >> 7;
  int n1_0 = (blockIdx.x & 127) * 64;
  int panel = blockIdx.x;                // = b*128 + tile

  // phase 0: stage candidates (x,y,z,|x|^2)
  const float* x2 = xyz2 + b * 3 * 2048;
  for (int j = t; j < 2048; j += 256) {
    float cx = x2[j], cy = x2[2048 + j], cz = x2[4096 + j];
    float nsq = (cx * cx + cy * cy) + cz * cz;
    lds.a.pts[j] = make_float4(cx, cy, cz, nsq);
  }
  __syncthreads();

  // phase 1: sliced top-3; lane = query, wave = slice (broadcast LDS reads)
  {
    int p = t & 63, s = t >> 6;
    int n1 = n1_0 + p;
    const float* x1 = xyz1 + b * 3 * 8192;
    float bx = x1[n1], by = x1[8192 + n1], bz = x1[16384 + n1];
    float n1sq = (bx * bx + by * by) + bz * bz;
    float nx = -2.f * bx, ny = -2.f * by, nz = -2.f * bz;
    float d0 = 3.4e38f, d1 = 3.4e38f, d2 = 3.4e38f;
    int i0 = 0, i1 = 0, i2 = 0;
    int jb = s * 512;
#pragma unroll 4
    for (int jj = 0; jj < 512; ++jj) {
      float4 c = lds.a.pts[jb + jj];
      float sq = fmaf(nx, c.x, fmaf(ny, c.y, fmaf(nz, c.z, n1sq + c.w)));
      int j = jb + jj;
      bool c0 = sq < d0, c1 = sq < d1, c2 = sq < d2;
      d2 = c1 ? d1 : (c2 ? sq : d2);  i2 = c1 ? i1 : (c2 ? j : i2);
      d1 = c0 ? d0 : (c1 ? sq : d1); i1 = c0 ? i0 : (c1 ? j : i1);
      d0 = c0 ? sq : d0;             i0 = c0 ? j : i0;
    }
    lds.a.md[t * 3 + 0] = d0; lds.a.md[t * 3 + 1] = d1; lds.a.md[t * 3 + 2] = d2;
    lds.a.mi[t * 3 + 0] = i0; lds.a.mi[t * 3 + 1] = i1; lds.a.mi[t * 3 + 2] = i2;
  }
  __syncthreads();
  if (t < 64) {
    // merge slices s=0..3 in ascending-index order (preserves tie-break)
    float d0 = 3.4e38f, d1 = 3.4e38f, d2 = 3.4e38f;
    int i0 = 0, i1 = 0, i2 = 0;
#pragma unroll
    for (int s = 0; s < 4; ++s) {
#pragma unroll
      for (int k = 0; k < 3; ++k) {
        float d = lds.a.md[(s * 64 + t) * 3 + k];
        int i = lds.a.mi[(s * 64 + t) * 3 + k];
        bool c0 = d < d0, c1 = d < d1, c2 = d < d2;
        d2 = c1 ? d1 : (c2 ? d : d2);  i2 = c1 ? i1 : (c2 ? i : i2);
        d1 = c0 ? d0 : (c1 ? d : d1); i1 = c0 ? i0 : (c1 ? i : i1);
        d0 = c0 ? d : d0;             i0 = c0 ? i : i0;
      }
    }
    float e0 = fmaxf(d0, 1e-10f), e1 = fmaxf(d1, 1e-10f), e2 = fmaxf(d2, 1e-10f);
    float w0 = 1.0f / e0, w1 = 1.0f / e1, w2 = 1.0f / e2;
    float sm = (w0 + w1) + w2;
    wts[t * 3 + 0] = w0 / sm; wts[t * 3 + 1] = w1 / sm; wts[t * 3 + 2] = w2 / sm;
    idxs[t * 3 + 0] = i0 * 256; idxs[t * 3 + 1] = i1 * 256; idxs[t * 3 + 2] = i2 * 256;
  }
  __syncthreads();

  // phase 2: interp 256 channels (thread = channel), write xb blocked
  {
    const u16* f2tb = f2t + (size_t)b * 2048 * 256;
    size_t xbase = (size_t)panel * 24576 + (size_t)((t >> 5) * 2048) + (t & 31);
#pragma unroll 4
    for (int p = 0; p < 64; ++p) {
      int j0 = idxs[p * 3 + 0], j1 = idxs[p * 3 + 1], j2 = idxs[p * 3 + 2];
      float w0 = wts[p * 3 + 0], w1 = wts[p * 3 + 1], w2 = wts[p * 3 + 2];
      float v = (w0 * b2f(f2tb[j0 + t]) + w1 * b2f(f2tb[j1 + t]))
                + w2 * b2f(f2tb[j2 + t]);
      xb[xbase + p * 32] = f2b(v);
    }
  }
  __syncthreads();   // before aliasing lds.a with lds.f1t

  // phase 3: skip features (channels 256..383) via LDS transpose
  {
    const float* f1b = f1 + (size_t)b * 128 * 8192 + n1_0;
    for (int it = 0; it < 32; ++it) {
      int c = it * 4 + (t >> 6);
      int n = t & 63;
      lds.f1t[c * 65 + n] = f1b[(size_t)c * 8192 + n];
    }
    __syncthreads();
    for (int it = 0; it < 32; ++it) {
      int v = it * 256 + t;
      int c = v & 127, p = v >> 7;
      float val = lds.f1t[c * 65 + p];
      xb[(size_t)panel * 24576 + (size_t)(8 + (c >> 5)) * 2048 + p * 32 + (c & 31)] = f2b(val);
    }
  }
}

// ---------------------------------------------------------------------------
// Streaming GEMM, no LDS, no barriers: out[o][bn]=act(al[o]*sum W*x + bt[o]).
// block: 256 threads (4 waves), tile 256(o) x 64(n), mfma 16x16x32 bf16.
// Each wave loads its fragments straight from the blocked global layouts:
//   A (weights)  wb  [kt][256o][32k]  -- L1/L2-resident, shared by all blocks
//   B (acts)     xin [panel][kt][64n][32k]
// Per-wave fragment loads are 64 lanes x 16B covering one contiguous 1KB span.
// FINAL=false -> pack 4 consecutive-o bf16 -> 8B stores, blocked y layout
// FINAL=true  -> f32 out [b][256][8192] + BN + ReLU
// ---------------------------------------------------------------------------
template <int KT, bool FINAL>
__global__ __launch_bounds__(256, 3) void gemm_kernel(
    const u16* __restrict__ xin, const u16* __restrict__ wb,
    const float* __restrict__ alpha, const float* __restrict__ beta,
    u16* __restrict__ yout, float* __restrict__ fout) {
  int t = threadIdx.x;
  int panel = blockIdx.x;
  int w = t >> 6, lane = t & 63, l15 = lane & 15, quad = lane >> 4;

  f32x4 acc[4][4];
#pragma unroll
  for (int m = 0; m < 4; ++m)
#pragma unroll
    for (int n = 0; n < 4; ++n)
      acc[m][n] = (f32x4){0.f, 0.f, 0.f, 0.f};

  const u16* aw = wb + (size_t)(w * 64 + l15) * 32 + quad * 8;
  const u16* bx = xin + (size_t)panel * (KT * 2048) + (size_t)l15 * 32 + quad * 8;

#pragma unroll 2
  for (int kt = 0; kt < KT; ++kt) {
    short8 af[4], bf[4];
#pragma unroll
    for (int m = 0; m < 4; ++m)
      af[m] = *(const short8*)(aw + kt * 8192 + m * 512);
#pragma unroll
    for (int n = 0; n < 4; ++n)
      bf[n] = *(const short8*)(bx + kt * 2048 + n * 512);
#pragma unroll
    for (int m = 0; m < 4; ++m)
#pragma unroll
      for (int n = 0; n < 4; ++n)
        acc[m][n] = __builtin_amdgcn_mfma_f32_16x16x32_bf16(af[m], bf[n], acc[m][n], 0, 0, 0);
  }

  float al[4][4], bt[4][4];
#pragma unroll
  for (int m = 0; m < 4; ++m)
#pragma unroll
    for (int r = 0; r < 4; ++r) {
      int o = w * 64 + m * 16 + quad * 4 + r;
      al[m][r] = alpha[o];
      bt[m][r] = beta[o];
    }

  if (FINAL) {
#pragma unroll
    for (int m = 0; m < 4; ++m)
#pragma unroll
      for (int n = 0; n < 4; ++n)
#pragma unroll
        for (int r = 0; r < 4; ++r) {
          int o = w * 64 + m * 16 + quad * 4 + r;
          int col = n * 16 + l15;
          int bn = panel * 64 + col;
          int bb = bn >> 13, n1 = bn & 8191;
          float vv = fmaxf(fmaf(al[m][r], acc[m][n][r], bt[m][r]), 0.f);
          fout[(size_t)(bb * 256 + o) * 8192 + n1] = vv;
        }
  } else {
    // lane's 4 acc regs are 4 consecutive o -> one packed 8B store each (m,n)
    u16* yp = yout + (size_t)panel * 16384;
#pragma unroll
    for (int m = 0; m < 4; ++m)
#pragma unroll
      for (int n = 0; n < 4; ++n) {
        int col = n * 16 + l15;
        ushort4 pk;
        pk.x = f2b(fmaxf(fmaf(al[m][0], acc[m][n][0], bt[m][0]), 0.f));
        pk.y = f2b(fmaxf(fmaf(al[m][1], acc[m][n][1], bt[m][1]), 0.f));
        pk.z = f2b(fmaxf(fmaf(al[m][2], acc[m][n][2], bt[m][2]), 0.f));
        pk.w = f2b(fmaxf(fmaf(al[m][3], acc[m][n][3], bt[m][3]), 0.f));
        *(ushort4*)(yp + (size_t)(w * 2 + (m >> 1)) * 2048 + col * 32 +
                    (m & 1) * 16 + quad * 4) = pk;
      }
  }
}

// ---------------------------------------------------------------------------
// ws layout (bytes):
//   [0,          50331648)  xb   bf16 [1024 panels][12][64][32]   48 MB
//   [50331648,   83886080)  y1   bf16 [1024][8][64][32]           32 MB
//      (f2t bf16 8 MB aliases the start of y1 — dead before y1 is written)
//   [83886080,   84082688)  w1b  bf16 blocked
//   [84082688,   84213760)  w2b  bf16 blocked
//   [84213760,   84217856)  al1/bt1/al2/bt2 f32
// total ~80.3 MB
// ---------------------------------------------------------------------------
extern "C" void kernel_launch(void* const* d_in, const int* in_sizes, int n_in,
                              void* d_out, int out_size, void* d_ws, size_t ws_size,
                              hipStream_t stream) {
  const float* xyz1 = (const float*)d_in[0];
  const float* xyz2 = (const float*)d_in[1];
  const float* f1   = (const float*)d_in[2];
  const float* f2   = (const float*)d_in[3];
  const float* w1   = (const float*)d_in[4];
  const float* b1   = (const float*)d_in[5];
  const float* g1   = (const float*)d_in[6];
  const float* be1  = (const float*)d_in[7];
  const float* m1   = (const float*)d_in[8];
  const float* v1   = (const float*)d_in[9];
  const float* w2   = (const float*)d_in[10];
  const float* b2   = (const float*)d_in[11];
  const float* g2   = (const float*)d_in[12];
  const float* be2  = (const float*)d_in[13];
  const float* m2   = (const float*)d_in[14];
  const float* v2   = (const float*)d_in[15];

  char* ws = (char*)d_ws;
  u16* xb   = (u16*)(ws);
  u16* y1   = (u16*)(ws + 50331648);
  u16* f2t  = (u16*)(ws + 50331648);   // aliases y1 region; dead before y1 write
  u16* w1b  = (u16*)(ws + 83886080);
  u16* w2b  = (u16*)(ws + 84082688);
  float* al1 = (float*)(ws + 84213760);
  float* bt1 = (float*)(ws + 84214784);
  float* al2 = (float*)(ws + 84215808);
  float* bt2 = (float*)(ws + 84216832);
  float* out = (float*)d_out;

  prep_kernel<<<642, 256, 0, stream>>>(w1, b1, g1, be1, m1, v1,
                                       w2, b2, g2, be2, m2, v2,
                                       w1b, w2b, al1, bt1, al2, bt2);
  transpose_f2_kernel<<<dim3(64, 8, 8), 256, 0, stream>>>(f2, f2t);
  knn_interp_kernel<<<1024, 256, 0, stream>>>(xyz1, xyz2, f1, f2t, xb);
  gemm_kernel<12, false><<<1024, 256, 0, stream>>>(xb, w1b, al1, bt1, y1, nullptr);
  gemm_kernel<8, true><<<1024, 256, 0, stream>>>(y1, w2b, al2, bt2, nullptr, out);
}